// Round 4
// baseline (119.533 us; speedup 1.0000x reference)
//
#include <hip/hip_runtime.h>
#include <math.h>

// Problem constants (match reference)
#define NB 128
#define NF 2048
#define NE 256
#define NF4 (NE / 4)  // 64 float4 per fact row per tensor

#define WAVES_PER_BLOCK 4
#define FACTS_PER_WAVE 16
#define FACTS_PER_BLOCK (WAVES_PER_BLOCK * FACTS_PER_WAVE)  // 64
#define CHUNKS_PER_B (NF / FACTS_PER_BLOCK)                 // 32
#define NPASS (FACTS_PER_WAVE / 2)                          // 8 passes, 2 facts each
#define NSLOT (CHUNKS_PER_B * WAVES_PER_BLOCK)              // 128 per-wave slots per b

__device__ __forceinline__ float sqd4(float4 a, float4 b) {
    float dx = a.x - b.x;
    float dy = a.y - b.y;
    float dz = a.z - b.z;
    float dw = a.w - b.w;
    return dx * dx + dy * dy + dz * dz + dw * dw;
}

// Layout: 32 lanes per fact (seg covers float4 seg and seg+32), 2 facts per
// pass (sub = lane>>5), 8 fully-unrolled passes = 16 facts per wave.
// Fact indices are CLAMPED to nb-1 (duplicate reads masked out of the min by
// the f<nb predicate) so every pass is compile-time. TRIPLE buffer: passes
// k+1 and k+2 are in flight while computing pass k -> 12 outstanding 1KB
// loads per wave, covering ~900cy memory latency with 4 waves/SIMD.
// No block reduce: each wave writes its own slot (no LDS, no barriers).
__global__ __launch_bounds__(256, 4) void nkb_min_kernel(
    const float* __restrict__ rel,
    const float* __restrict__ arg1,
    const float* __restrict__ arg2,
    const float* __restrict__ fact_rel,
    const float* __restrict__ fact_arg1,
    const float* __restrict__ fact_arg2,
    const int* __restrict__ nb_facts,
    float* __restrict__ ws)
{
    const int b = blockIdx.x >> 5;        // / CHUNKS_PER_B
    const int chunk = blockIdx.x & 31;    // % CHUNKS_PER_B
    const int nb = nb_facts[b];
    const int tid = threadIdx.x;
    const int wave = tid >> 6;
    const int lane = tid & 63;
    const int sub = lane >> 5;   // which of the 2 facts in a pass
    const int seg = lane & 31;   // float4 segment (covers seg and seg+32)

    const int fbeg = chunk * FACTS_PER_BLOCK + wave * FACTS_PER_WAVE;
    float dmin = INFINITY;

    if (fbeg < nb) {
        const int fmax = nb - 1;  // nb >= 1 here
        const float4* fr  = reinterpret_cast<const float4*>(fact_rel  + (size_t)b * NF * NE);
        const float4* fa1 = reinterpret_cast<const float4*>(fact_arg1 + (size_t)b * NF * NE);
        const float4* fa2 = reinterpret_cast<const float4*>(fact_arg2 + (size_t)b * NF * NE);

        float4 buf[3][6];  // [depth][2 segs x 3 tensors]; all indices
                           // compile-time after unroll -> stays in VGPRs

#define LOAD_PASS(K, D)                                          \
        {                                                        \
            const int f_ = min(fbeg + 2 * (K) + sub, fmax);      \
            const size_t base_ = (size_t)f_ * NF4 + seg;         \
            D[0] = fr [base_];  D[1] = fr [base_ + 32];          \
            D[2] = fa1[base_];  D[3] = fa1[base_ + 32];          \
            D[4] = fa2[base_];  D[5] = fa2[base_ + 32];          \
        }

        // Prologue: 12 fact loads in flight before anything waits on memory.
        LOAD_PASS(0, buf[0]);
        LOAD_PASS(1, buf[1]);

        // Query fragments (6 float4 = 24 VGPRs), issued after fact loads.
        const float4* qr  = reinterpret_cast<const float4*>(rel  + (size_t)b * NE);
        const float4* qa1 = reinterpret_cast<const float4*>(arg1 + (size_t)b * NE);
        const float4* qa2 = reinterpret_cast<const float4*>(arg2 + (size_t)b * NE);
        float4 q[6];
        q[0] = qr [seg];  q[1] = qr [seg + 32];
        q[2] = qa1[seg];  q[3] = qa1[seg + 32];
        q[4] = qa2[seg];  q[5] = qa2[seg + 32];

        #pragma unroll
        for (int k = 0; k < NPASS; ++k) {
            if (k + 2 < NPASS) LOAD_PASS(k + 2, buf[(k + 2) % 3]);
            const float4* A = buf[k % 3];
            float acc = sqd4(q[0], A[0]) + sqd4(q[1], A[1]) + sqd4(q[2], A[2])
                      + sqd4(q[3], A[3]) + sqd4(q[4], A[4]) + sqd4(q[5], A[5]);
            // Sum within each 32-lane group (both facts reduced simultaneously).
            #pragma unroll
            for (int s = 1; s < 32; s <<= 1) acc += __shfl_xor(acc, s);
            if (fbeg + 2 * k + sub < nb) dmin = fminf(dmin, acc);
        }
#undef LOAD_PASS
        // Combine the two 32-lane groups' minima.
        dmin = fminf(dmin, __shfl_xor(dmin, 32));
    }

    // Per-wave slot write: no LDS, no barriers, waves retire independently.
    // ws layout [slot][b] so finish_kernel reads coalesced. Every wave (live
    // or dead) writes exactly once -> ws fully rewritten each call.
    if (lane == 0) ws[(chunk * WAVES_PER_BLOCK + wave) * NB + b] = dmin;
}

__global__ void finish_kernel(const float* __restrict__ ws,
                              const int* __restrict__ nb_facts,
                              float* __restrict__ out) {
    const int b = threadIdx.x;  // 128 threads, 1 block
    float m = INFINITY;
    for (int c = 0; c < NSLOT; ++c)
        m = fminf(m, ws[c * NB + b]);
    float v = 0.0f;
    if (nb_facts[b] > 0 && isfinite(m)) v = expf(-m);
    out[b] = v;
}

extern "C" void kernel_launch(void* const* d_in, const int* in_sizes, int n_in,
                              void* d_out, int out_size, void* d_ws, size_t ws_size,
                              hipStream_t stream) {
    const float* rel       = (const float*)d_in[0];
    const float* arg1      = (const float*)d_in[1];
    const float* arg2      = (const float*)d_in[2];
    const float* fact_rel  = (const float*)d_in[3];
    const float* fact_arg1 = (const float*)d_in[4];
    const float* fact_arg2 = (const float*)d_in[5];
    const int*   nb_facts  = (const int*)d_in[6];
    float* out = (float*)d_out;
    float* ws  = (float*)d_ws;

    // 1) masked, triple-buffered min of squared distances; each wave writes
    //    its slot-min (dead waves write +inf) -> ws fully rewritten per call.
    const int grid = NB * CHUNKS_PER_B;  // 4096 blocks
    nkb_min_kernel<<<grid, 256, 0, stream>>>(rel, arg1, arg2,
                                             fact_rel, fact_arg1, fact_arg2,
                                             nb_facts, ws);

    // 2) out[b] = nb>0 ? exp(-min) : 0
    finish_kernel<<<1, NB, 0, stream>>>(ws, nb_facts, out);
}

// Round 5
// 26.434 us; speedup vs baseline: 4.5220x; 4.5220x over previous
//
#include <hip/hip_runtime.h>
#include <math.h>

// Problem constants (match reference)
#define NB 128
#define NF 2048
#define NE 256
#define NF4 (NE / 4)   // 64 float4 per 256-float row

#define WAVES_PER_BLOCK 4
#define FACTS_PER_WAVE 16
#define FACTS_PER_BLOCK 64
#define CHUNKS_PER_B 32
#define NPASS 4                                  // 4 facts per pass, 4 passes
#define NSLOT (CHUNKS_PER_B * WAVES_PER_BLOCK)   // 128 mask slots per b

// Branch-and-bound threshold. expf(-x) == 0.0f exactly for x > ~104
// (e^-104 < 2^-150, rounds to +0). Squared distance accumulates
// non-negatively over dims, so prefix_d > T  =>  full d > T  =>  score is
// exactly 0.0f in BOTH reference and ours. T=110 leaves margin; any fact
// with a nonzero score has full d <= 104, hence prefix <= 104 < 110 and is
// flagged for the exact slow path. Expected candidates at this input
// distribution (prefix ~ N(256,32)): ~1e-6 per fact — slow path ~never runs,
// but is exact when it does.
#define THRESH 110.0f

__device__ __forceinline__ float sqd4(float4 a, float4 b) {
    float dx = a.x - b.x;
    float dy = a.y - b.y;
    float dz = a.z - b.z;
    float dw = a.w - b.w;
    return dx * dx + dy * dy + dz * dz + dw * dw;
}

// Phase 1: stream ONLY the first 128 floats (512 B) of each fact_rel row and
// flag facts whose 128-dim prefix distance <= THRESH. 16 lanes per fact
// (seg = lane&15 covers float4 seg and seg+16), 4 facts per pass
// (sub = lane>>4), 4 fully-unrolled passes (indices clamped to nb-1; clamped
// duplicates are excluded from the mask by the f<nb predicate).
// Every wave (live or dead) writes its 16-bit candidate mask -> ws fully
// rewritten every call (harness poisons ws with 0xAA once).
__global__ __launch_bounds__(256, 8) void nkb_prefix_kernel(
    const float* __restrict__ rel,
    const float* __restrict__ fact_rel,
    const int* __restrict__ nb_facts,
    unsigned int* __restrict__ ws_mask)
{
    const int b = blockIdx.x >> 5;        // / CHUNKS_PER_B
    const int chunk = blockIdx.x & 31;    // % CHUNKS_PER_B
    const int nb = nb_facts[b];
    const int tid = threadIdx.x;
    const int wave = tid >> 6;
    const int lane = tid & 63;
    const int sub = lane >> 4;   // which of the 4 facts in a pass
    const int seg = lane & 15;   // float4 segment within the 128-dim prefix

    const int fbeg = chunk * FACTS_PER_BLOCK + wave * FACTS_PER_WAVE;
    unsigned int wmask = 0;

    if (fbeg < nb) {
        const int fmax = nb - 1;  // nb >= 1 here
        // Query prefix: 2 float4 = 8 VGPRs (first 128 floats of rel row).
        const float4* qr = reinterpret_cast<const float4*>(rel + (size_t)b * NE);
        float4 q0 = qr[seg];
        float4 q1 = qr[seg + 16];

        const float4* fr = reinterpret_cast<const float4*>(fact_rel + (size_t)b * NF * NE);

        float4 A0, A1, B0, B1;
        {
            const int f = min(fbeg + sub, fmax);
            const float4* p = fr + (size_t)f * NF4 + seg;
            A0 = p[0];
            A1 = p[16];
        }

        #pragma unroll
        for (int k = 0; k < NPASS; ++k) {
            if (k + 1 < NPASS) {  // double-buffer: next pass's 2 loads in flight
                const int f = min(fbeg + 4 * (k + 1) + sub, fmax);
                const float4* p = fr + (size_t)f * NF4 + seg;
                B0 = p[0];
                B1 = p[16];
            }
            float acc = sqd4(q0, A0) + sqd4(q1, A1);
            // Sum within each 16-lane group: 4 facts reduced simultaneously.
            #pragma unroll
            for (int s = 1; s < 16; s <<= 1) acc += __shfl_xor(acc, s);

            const bool cand = (acc <= THRESH) && (fbeg + 4 * k + sub < nb);
            const unsigned long long bal = __ballot(cand);
            // Group j's verdict sits (replicated) at lanes 16j..16j+15.
            const unsigned int bits =
                  (unsigned int)( (bal        & 1ull)
                               | ((bal >> 16) & 1ull) << 1
                               | ((bal >> 32) & 1ull) << 2
                               | ((bal >> 48) & 1ull) << 3);
            wmask |= bits << (4 * k);  // bit p = fact fbeg+p (p = 4k+sub)

            if (k + 1 < NPASS) { A0 = B0; A1 = B1; }
        }
    }

    if (lane == 0)
        ws_mask[(size_t)b * NSLOT + chunk * WAVES_PER_BLOCK + wave] = wmask;
}

// Phase 2 + output: one block per b. Typically zero candidate bits -> out=0
// (exactly matching reference, whose scores all underflow). For each flagged
// fact, recompute the FULL 768-dim squared distance block-parallel (exact),
// take the min, out = expf(-min) (underflows to 0 itself if still > ~104).
__global__ __launch_bounds__(256) void nkb_finish_kernel(
    const float* __restrict__ rel,
    const float* __restrict__ arg1,
    const float* __restrict__ arg2,
    const float* __restrict__ fact_rel,
    const float* __restrict__ fact_arg1,
    const float* __restrict__ fact_arg2,
    const unsigned int* __restrict__ ws_mask,
    float* __restrict__ out)
{
    const int b = blockIdx.x;
    const int tid = threadIdx.x;
    const int wave = tid >> 6;
    const int lane = tid & 63;

    __shared__ unsigned int smask[NSLOT];
    __shared__ float swsum[4];
    __shared__ float sbest;

    if (tid < NSLOT) smask[tid] = ws_mask[(size_t)b * NSLOT + tid];
    if (tid == 0) sbest = INFINITY;
    __syncthreads();

    // Block-uniform candidate scan (smask identical for all threads, so the
    // loop structure — and its barriers — are uniform).
    for (int s = 0; s < NSLOT; ++s) {
        unsigned int m = smask[s];
        while (m) {
            const int p = __ffs(m) - 1;
            m &= m - 1;
            const int f = ((s >> 2) << 6) + ((s & 3) << 4) + p;  // chunk*64+wave*16+p

            // Exact full distance, 256 threads x 3 dims each.
            const size_t fb = (size_t)b * NF * NE + (size_t)f * NE + tid;
            const float dr = fact_rel [fb] - rel [b * NE + tid];
            const float d1 = fact_arg1[fb] - arg1[b * NE + tid];
            const float d2 = fact_arg2[fb] - arg2[b * NE + tid];
            float v = dr * dr + d1 * d1 + d2 * d2;
            #pragma unroll
            for (int sh = 1; sh < 64; sh <<= 1) v += __shfl_xor(v, sh);
            if (lane == 0) swsum[wave] = v;
            __syncthreads();
            if (tid == 0) {
                const float d = swsum[0] + swsum[1] + swsum[2] + swsum[3];
                sbest = fminf(sbest, d);
            }
            __syncthreads();
        }
    }

    if (tid == 0) {
        // No candidates: sbest=+inf, expf(-inf)=0 — but keep it explicit.
        out[b] = isfinite(sbest) ? expf(-sbest) : 0.0f;
    }
}

extern "C" void kernel_launch(void* const* d_in, const int* in_sizes, int n_in,
                              void* d_out, int out_size, void* d_ws, size_t ws_size,
                              hipStream_t stream) {
    const float* rel       = (const float*)d_in[0];
    const float* arg1      = (const float*)d_in[1];
    const float* arg2      = (const float*)d_in[2];
    const float* fact_rel  = (const float*)d_in[3];
    const float* fact_arg1 = (const float*)d_in[4];
    const float* fact_arg2 = (const float*)d_in[5];
    const int*   nb_facts  = (const int*)d_in[6];
    float* out = (float*)d_out;
    unsigned int* ws_mask = (unsigned int*)d_ws;

    // 1) prefix screen: reads only 512B/fact of fact_rel for valid facts
    const int grid = NB * CHUNKS_PER_B;  // 4096 blocks
    nkb_prefix_kernel<<<grid, 256, 0, stream>>>(rel, fact_rel, nb_facts, ws_mask);

    // 2) exact slow path for flagged facts (typically none) + output
    nkb_finish_kernel<<<NB, 256, 0, stream>>>(rel, arg1, arg2,
                                              fact_rel, fact_arg1, fact_arg2,
                                              ws_mask, out);
}